// Round 6
// baseline (101.315 us; speedup 1.0000x reference)
//
#include <hip/hip_runtime.h>
#include <math.h>

// SparseMultiheadAttention B=2,H=16,S=2048,DH=64, STRIDE=128, EXPR=32, bidirectional.
// Mask factorization (HW-validated rounds 0-2):
//   allowed(i,c) = (c&127)>=96 | ((c&127)==0 && c>0) | ((c>>7)==a(i))
//   a(i) = (i>>7) - ((i&127)==0 && i>0)
// Schedule (R5 = R4 + T14 async-STAGE split):
//   stage_load(s+1) -> compute(s) -> stage_write(s+1) -> barrier
// so global-load latency hides under compute instead of serializing before it.
// Block = 64 rows (4 waves x 16 rows), grid = 32 bh x 32 row-blocks = 1024.
// 64-col segments, A = row-block's 128-block = R64>>1:
//   s0..7 : summary pairs [256s+96,+128) u [256s+224,+256)       no mask
//   s8    : local [128A, +64)                                     mask a_row==A
//   s9    : local [128A+64,+96) (32) + checkpoints {128k,k=1..15}+pad (16), nn=3
//   s10/11: special block A-1 (R64 even && >0 only); wave 0 computes.
// Coverage verified per-row (col 128A masked in checkpoint tile, unmasked in s8;
// col 128(A-1) masked in checkpoint tile for special row, unmasked in s10).

namespace {

constexpr int kS = 2048, kD = 64;

typedef __attribute__((ext_vector_type(8))) short short8;
typedef __attribute__((ext_vector_type(4))) float f32x4;
typedef __attribute__((ext_vector_type(4))) unsigned int u32x4;

__device__ __forceinline__ unsigned f2bf(float f) {           // RNE (Q only)
    unsigned u = __builtin_bit_cast(unsigned, f);
    u += 0x7fffu + ((u >> 16) & 1u);
    return u >> 16;
}
__device__ __forceinline__ unsigned pk2(float a, float b) {   // RNE pair
    return f2bf(a) | (f2bf(b) << 16);
}
__device__ __forceinline__ unsigned pkt(float a, float b) {   // truncating pair: 1 v_perm
    return __builtin_amdgcn_perm(__builtin_bit_cast(unsigned, b),
                                 __builtin_bit_cast(unsigned, a), 0x07060302u);
}

__device__ __forceinline__ int seglen(int s) { return s == 9 ? 48 : (s == 11 ? 32 : 64); }

__device__ __forceinline__ int colOf(int s, int p, int A) {
    if (s < 8)  return 256 * s + (p < 32 ? 96 + p : 192 + p);
    if (s == 8) return 128 * A + p;
    if (s == 9) {
        if (p < 32) return 128 * A + 64 + p;
        const int k = p - 31;                 // 1..16
        return k < 16 ? 128 * k : 2047;       // p=47 pad (always masked)
    }
    if (s == 10) return 128 * (A - 1) + p;
    return 128 * (A - 1) + 64 + p;            // s==11
}
__device__ __forceinline__ bool maskOf(int s, int p, int a_row, int A) {
    if (s < 8)  return true;
    if (s == 8) return a_row == A;
    if (s == 9) return p < 32 ? (a_row == A) : (p < 47 && a_row != (p - 31));
    return a_row == A - 1;                    // s==10/11
}

__global__ __launch_bounds__(256, 4) void sparse_attn4(
    const float* __restrict__ Q, const float* __restrict__ K,
    const float* __restrict__ V, float* __restrict__ Out)
{
    // [0,16K):   K dbuf 2 x 8KB  [c(64)][d(64)] bf16, swz byte ^= (c&7)<<4
    // [16K,32K): V^T dbuf 2 x 8KB [d(64)][c(64)] bf16, swz byte ^= (d&7)<<4
    // [32K,40K): ps 4 waves x 2KB [row(16)][c(64)] bf16, swz byte ^= (row&7)<<4
    __shared__ __align__(16) unsigned char lds[40960];

    const int tid = threadIdx.x;
    const int wv = tid >> 6;
    const int l = tid & 63, g = l >> 4, lm = l & 15;
    const int bh = blockIdx.x >> 5, R64 = blockIdx.x & 31;
    const int A = R64 >> 1;
    const int rowbase = R64 * 64 + wv * 16;
    const bool spec = ((R64 & 1) == 0) && (R64 > 0);
    const int nseg = spec ? 12 : 10;

    const float* Qb = Q + (size_t)bh * kS * kD;
    const float* Kb = K + (size_t)bh * kS * kD;
    const float* Vb = V + (size_t)bh * kS * kD;

    // Q A-fragment (row = lm, k = g*8+j+32kk), pre-scaled by 1/8, RNE
    short8 qa[2];
#pragma unroll
    for (int kk = 0; kk < 2; ++kk) {
        const float* qp = Qb + (size_t)(rowbase + lm) * kD + kk*32 + g*8;
        float4 a = *(const float4*)qp;
        float4 b = *(const float4*)(qp + 4);
        u32x4 t;
        t.x = pk2(a.x*0.125f, a.y*0.125f);
        t.y = pk2(a.z*0.125f, a.w*0.125f);
        t.z = pk2(b.x*0.125f, b.y*0.125f);
        t.w = pk2(b.z*0.125f, b.w*0.125f);
        qa[kk] = __builtin_bit_cast(short8, t);
    }

    int arow[4];
#pragma unroll
    for (int i = 0; i < 4; ++i) {
        const int ig = rowbase + g*4 + i;
        arow[i] = (ig >> 7) - (((ig & 127) == 0 && ig > 0) ? 1 : 0);
    }

    float mrun[4], lpar[4];
    f32x4 o[4];
#pragma unroll
    for (int i = 0; i < 4; ++i) { mrun[i] = -1e30f; lpar[i] = 0.f; }
#pragma unroll
    for (int nv = 0; nv < 4; ++nv) o[nv] = (f32x4){0.f,0.f,0.f,0.f};

    // T14 staging registers: K 4xfloat4, V 8xfloat2 in flight across compute
    float4 kreg[4];
    float2 vreg[8];

    auto stage_load = [&](int s) {        // issue global loads only
        const int len = seglen(s);
        const int c = tid >> 2, q4 = tid & 3;
        if (c < len) {
            const int col = colOf(s, c, A);
            const float* kp = Kb + (size_t)col * kD + q4*16;
            kreg[0] = *(const float4*)(kp);
            kreg[1] = *(const float4*)(kp + 4);
            kreg[2] = *(const float4*)(kp + 8);
            kreg[3] = *(const float4*)(kp + 12);
        }
        const int c0 = (tid >> 5) * 8, d0 = (tid & 31) * 2;
        if (c0 < len) {
#pragma unroll
            for (int j = 0; j < 8; ++j) {
                const int col = colOf(s, c0 + j, A);
                vreg[j] = *(const float2*)(Vb + (size_t)col * kD + d0);
            }
        }
    };

    auto stage_write = [&](int s, int buf) {   // vmcnt-wait + pack + LDS write
        unsigned char* ksb = lds + buf * 8192;
        unsigned char* vsb = lds + 16384 + buf * 8192;
        const int len = seglen(s);
        const int c = tid >> 2, q4 = tid & 3;
        if (c < len) {
            u32x4 lo, hi;
            lo.x = pkt(kreg[0].x,kreg[0].y); lo.y = pkt(kreg[0].z,kreg[0].w);
            lo.z = pkt(kreg[1].x,kreg[1].y); lo.w = pkt(kreg[1].z,kreg[1].w);
            hi.x = pkt(kreg[2].x,kreg[2].y); hi.y = pkt(kreg[2].z,kreg[2].w);
            hi.z = pkt(kreg[3].x,kreg[3].y); hi.w = pkt(kreg[3].z,kreg[3].w);
            const unsigned b  = (unsigned)(c*128 + q4*32);
            const unsigned sw = ((unsigned)(c & 7)) << 4;
            *(u32x4*)(ksb + (b ^ sw))        = lo;
            *(u32x4*)(ksb + ((b ^ sw) ^ 16)) = hi;
        }
        const int c0 = (tid >> 5) * 8, d0 = (tid & 31) * 2;
        if (c0 < len) {
            u32x4 t0, t1;
            t0.x = pkt(vreg[0].x,vreg[1].x); t0.y = pkt(vreg[2].x,vreg[3].x);
            t0.z = pkt(vreg[4].x,vreg[5].x); t0.w = pkt(vreg[6].x,vreg[7].x);
            t1.x = pkt(vreg[0].y,vreg[1].y); t1.y = pkt(vreg[2].y,vreg[3].y);
            t1.z = pkt(vreg[4].y,vreg[5].y); t1.w = pkt(vreg[6].y,vreg[7].y);
            const unsigned b0 = (unsigned)(d0*128 + c0*2)     ^ (((unsigned)(d0 & 7)) << 4);
            const unsigned b1 = (unsigned)((d0+1)*128 + c0*2) ^ (((unsigned)((d0+1) & 7)) << 4);
            *(u32x4*)(vsb + b0) = t0;
            *(u32x4*)(vsb + b1) = t1;
        }
    };

    auto compute = [&](int s, int buf) {
        if (s >= 10 && wv != 0) return;      // special block: only wave 0's rows
        const int nn = (s == 9) ? 3 : ((s == 11) ? 2 : 4);
        const unsigned char* ksb = lds + buf * 8192;
        const unsigned char* vsb = lds + 16384 + buf * 8192;
        unsigned char* ps = lds + 32768 + wv * 2048;

        f32x4 sf[4];
#pragma unroll
        for (int n = 0; n < 4; ++n) sf[n] = (f32x4){0.f,0.f,0.f,0.f};

        __builtin_amdgcn_s_setprio(1);
#pragma unroll
        for (int n = 0; n < 4; ++n) if (n < nn) {
            const int c = lm + 16*n;
#pragma unroll
            for (int kk = 0; kk < 2; ++kk) {
                const unsigned byte = (unsigned)(c*128 + kk*64 + g*16) ^ (((unsigned)(c & 7)) << 4);
                const short8 kf = *(const short8*)(ksb + byte);
                sf[n] = __builtin_amdgcn_mfma_f32_16x16x32_bf16(qa[kk], kf, sf[n], 0, 0, 0);
            }
        }
        __builtin_amdgcn_s_setprio(0);

        if (s >= 8) {
#pragma unroll
            for (int n = 0; n < 4; ++n) if (n < nn) {
                const int p = lm + 16*n;
#pragma unroll
                for (int i = 0; i < 4; ++i)
                    if (!maskOf(s, p, arow[i], A)) sf[n][i] = -1e30f;
            }
        }

        // online softmax with defer-max (THR=8)
        float tmx[4]; bool need = false;
#pragma unroll
        for (int i = 0; i < 4; ++i) {
            float t = sf[0][i];
#pragma unroll
            for (int n = 1; n < 4; ++n) if (n < nn) t = fmaxf(t, sf[n][i]);
            t = fmaxf(t, __shfl_xor(t, 1));
            t = fmaxf(t, __shfl_xor(t, 2));
            t = fmaxf(t, __shfl_xor(t, 4));
            t = fmaxf(t, __shfl_xor(t, 8));
            tmx[i] = t;
            need = need || (t > mrun[i] + 8.f);
        }
        if (__any(need)) {
#pragma unroll
            for (int i = 0; i < 4; ++i) {
                const float nm = fmaxf(mrun[i], tmx[i]);
                const float al = __expf(mrun[i] - nm);
                mrun[i] = nm; lpar[i] *= al;
#pragma unroll
                for (int nv = 0; nv < 4; ++nv) o[nv][i] *= al;
            }
        }
        const int nwr = (nn + 1) & ~1;       // 4,4,2: zero-fill n=3 when nn==3
#pragma unroll
        for (int i = 0; i < 4; ++i) {
            const int row = g*4 + i;
            const unsigned sw = ((unsigned)(row & 7)) << 4;
            float psum = 0.f;
#pragma unroll
            for (int n = 0; n < 4; ++n) if (n < nwr) {
                const float p = (n < nn) ? __expf(sf[n][i] - mrun[i]) : 0.f;
                psum += p;
                const unsigned byte = ((unsigned)(row*128 + (lm + 16*n)*2)) ^ sw;
                *(unsigned short*)(ps + byte) = (unsigned short)(pkt(p, 0.f) & 0xffffu);
            }
            lpar[i] += psum;
        }

        short8 pa[2];
#pragma unroll
        for (int kpv = 0; kpv < 2; ++kpv) if (2*kpv < nn) {
            const unsigned byte = ((unsigned)(lm*128 + kpv*64 + g*16)) ^ (((unsigned)(lm & 7)) << 4);
            pa[kpv] = *(const short8*)(ps + byte);
        }
        __builtin_amdgcn_s_setprio(1);
#pragma unroll
        for (int nv = 0; nv < 4; ++nv)
#pragma unroll
        for (int kpv = 0; kpv < 2; ++kpv) if (2*kpv < nn) {
            const int vd = lm + 16*nv;
            const unsigned byte = ((unsigned)(vd*128 + kpv*64 + g*16)) ^ (((unsigned)(vd & 7)) << 4);
            const short8 vb = *(const short8*)(vsb + byte);
            o[nv] = __builtin_amdgcn_mfma_f32_16x16x32_bf16(pa[kpv], vb, o[nv], 0, 0, 0);
        }
        __builtin_amdgcn_s_setprio(0);
    };

    stage_load(0);
    stage_write(0, 0);
    __syncthreads();
    for (int s = 0; s < nseg; ++s) {
        const bool pre = (s + 1 < nseg);
        if (pre) stage_load(s + 1);          // issue loads EARLY (T14)
        compute(s, s & 1);                   // hides load latency
        if (pre) stage_write(s + 1, (s + 1) & 1);   // pack+write LATE
        __syncthreads();
    }

    // epilogue: reduce row sums across the 16-lane group, normalize, store fp32
#pragma unroll
    for (int i = 0; i < 4; ++i) {
        float v = lpar[i];
        v += __shfl_xor(v, 1);
        v += __shfl_xor(v, 2);
        v += __shfl_xor(v, 4);
        v += __shfl_xor(v, 8);
        const float inv = 1.f / v;
        float* op = Out + ((size_t)bh * kS + rowbase + g*4 + i) * kD + lm;
#pragma unroll
        for (int nv = 0; nv < 4; ++nv)
            op[16*nv] = o[nv][i] * inv;
    }
}

} // namespace

extern "C" void kernel_launch(void* const* d_in, const int* in_sizes, int n_in,
                              void* d_out, int out_size, void* d_ws, size_t ws_size,
                              hipStream_t stream) {
    const float* q = (const float*)d_in[0];
    const float* k = (const float*)d_in[1];
    const float* v = (const float*)d_in[2];
    // d_in[3] (mask) is a pure function of (S,STRIDE,EXPR) reproduced in-kernel.
    float* out = (float*)d_out;
    dim3 grid(1024), block(256);
    hipLaunchKernelGGL(sparse_attn4, grid, block, 0, stream, q, k, v, out);
}

// Round 7
// 72.968 us; speedup vs baseline: 1.3885x; 1.3885x over previous
//
#include <hip/hip_runtime.h>
#include <math.h>

// SparseMultiheadAttention B=2,H=16,S=2048,DH=64, STRIDE=128, EXPR=32, bidirectional.
// Mask factorization (HW-validated rounds 0-2):
//   allowed(i,c) = (c&127)>=96 | ((c&127)==0 && c>0) | ((c>>7)==a(i))
//   a(i) = (i>>7) - ((i&127)==0 && i>0)
// Schedule: stage_load(s+1) -> compute(s) -> stage_write(s+1) -> barrier (T14).
// R6 lesson: __launch_bounds__(256,4) clamped the allocator to 64 VGPR ->
// per-segment scratch spills (WRITE_SIZE 51 MB vs 16.8 MB output). Occupancy is
// LDS-capped (40KB -> 4 blocks/CU) anyway, so use plain (256) like the
// spill-free rounds 1-2 and let the allocator take ~128.
// Block = 64 rows (4 waves x 16 rows), grid = 32 bh x 32 row-blocks = 1024.
// 64-col segments, A = row-block's 128-block = R64>>1:
//   s0..7 : summary pairs [256s+96,+128) u [256s+224,+256)       no mask
//   s8    : local [128A, +64)                                     mask a_row==A
//   s9    : local [128A+64,+96) (32) + checkpoints {128k,k=1..15}+pad (16), nn=3
//   s10/11: special block A-1 (R64 even && >0 only); wave 0 computes.
// Coverage verified per-row (col 128A masked in checkpoint tile, unmasked in s8;
// col 128(A-1) masked in checkpoint tile for special row, unmasked in s10).

namespace {

constexpr int kS = 2048, kD = 64;

typedef __attribute__((ext_vector_type(8))) short short8;
typedef __attribute__((ext_vector_type(4))) float f32x4;
typedef __attribute__((ext_vector_type(4))) unsigned int u32x4;

__device__ __forceinline__ unsigned f2bf(float f) {           // RNE (Q only)
    unsigned u = __builtin_bit_cast(unsigned, f);
    u += 0x7fffu + ((u >> 16) & 1u);
    return u >> 16;
}
__device__ __forceinline__ unsigned pk2(float a, float b) {   // RNE pair
    return f2bf(a) | (f2bf(b) << 16);
}
__device__ __forceinline__ unsigned pkt(float a, float b) {   // truncating pair: 1 v_perm
    return __builtin_amdgcn_perm(__builtin_bit_cast(unsigned, b),
                                 __builtin_bit_cast(unsigned, a), 0x07060302u);
}

__device__ __forceinline__ int seglen(int s) { return s == 9 ? 48 : (s == 11 ? 32 : 64); }

__device__ __forceinline__ int colOf(int s, int p, int A) {
    if (s < 8)  return 256 * s + (p < 32 ? 96 + p : 192 + p);
    if (s == 8) return 128 * A + p;
    if (s == 9) {
        if (p < 32) return 128 * A + 64 + p;
        const int k = p - 31;                 // 1..16
        return k < 16 ? 128 * k : 2047;       // p=47 pad (always masked)
    }
    if (s == 10) return 128 * (A - 1) + p;
    return 128 * (A - 1) + 64 + p;            // s==11
}
__device__ __forceinline__ bool maskOf(int s, int p, int a_row, int A) {
    if (s < 8)  return true;
    if (s == 8) return a_row == A;
    if (s == 9) return p < 32 ? (a_row == A) : (p < 47 && a_row != (p - 31));
    return a_row == A - 1;                    // s==10/11
}

__global__ __launch_bounds__(256) void sparse_attn5(
    const float* __restrict__ Q, const float* __restrict__ K,
    const float* __restrict__ V, float* __restrict__ Out)
{
    // [0,16K):   K dbuf 2 x 8KB  [c(64)][d(64)] bf16, swz byte ^= (c&7)<<4
    // [16K,32K): V^T dbuf 2 x 8KB [d(64)][c(64)] bf16, swz byte ^= (d&7)<<4
    // [32K,40K): ps 4 waves x 2KB [row(16)][c(64)] bf16, swz byte ^= (row&7)<<4
    __shared__ __align__(16) unsigned char lds[40960];

    const int tid = threadIdx.x;
    const int wv = tid >> 6;
    const int l = tid & 63, g = l >> 4, lm = l & 15;
    const int bh = blockIdx.x >> 5, R64 = blockIdx.x & 31;
    const int A = R64 >> 1;
    const int rowbase = R64 * 64 + wv * 16;
    const bool spec = ((R64 & 1) == 0) && (R64 > 0);
    const int nseg = spec ? 12 : 10;

    const float* Qb = Q + (size_t)bh * kS * kD;
    const float* Kb = K + (size_t)bh * kS * kD;
    const float* Vb = V + (size_t)bh * kS * kD;

    // Q A-fragment (row = lm, k = g*8+j+32kk), pre-scaled by 1/8, RNE
    short8 qa[2];
#pragma unroll
    for (int kk = 0; kk < 2; ++kk) {
        const float* qp = Qb + (size_t)(rowbase + lm) * kD + kk*32 + g*8;
        float4 a = *(const float4*)qp;
        float4 b = *(const float4*)(qp + 4);
        u32x4 t;
        t.x = pk2(a.x*0.125f, a.y*0.125f);
        t.y = pk2(a.z*0.125f, a.w*0.125f);
        t.z = pk2(b.x*0.125f, b.y*0.125f);
        t.w = pk2(b.z*0.125f, b.w*0.125f);
        qa[kk] = __builtin_bit_cast(short8, t);
    }

    int arow[4];
#pragma unroll
    for (int i = 0; i < 4; ++i) {
        const int ig = rowbase + g*4 + i;
        arow[i] = (ig >> 7) - (((ig & 127) == 0 && ig > 0) ? 1 : 0);
    }

    float mrun[4], lpar[4];
    f32x4 o[4];
#pragma unroll
    for (int i = 0; i < 4; ++i) { mrun[i] = -1e30f; lpar[i] = 0.f; }
#pragma unroll
    for (int nv = 0; nv < 4; ++nv) o[nv] = (f32x4){0.f,0.f,0.f,0.f};

    // T14 staging registers: K 4xfloat4, V 8xfloat2 in flight across compute
    float4 kreg[4];
    float2 vreg[8];

    auto stage_load = [&](int s) {        // issue global loads only
        const int len = seglen(s);
        const int c = tid >> 2, q4 = tid & 3;
        if (c < len) {
            const int col = colOf(s, c, A);
            const float* kp = Kb + (size_t)col * kD + q4*16;
            kreg[0] = *(const float4*)(kp);
            kreg[1] = *(const float4*)(kp + 4);
            kreg[2] = *(const float4*)(kp + 8);
            kreg[3] = *(const float4*)(kp + 12);
        }
        const int c0 = (tid >> 5) * 8, d0 = (tid & 31) * 2;
        if (c0 < len) {
#pragma unroll
            for (int j = 0; j < 8; ++j) {
                const int col = colOf(s, c0 + j, A);
                vreg[j] = *(const float2*)(Vb + (size_t)col * kD + d0);
            }
        }
    };

    auto stage_write = [&](int s, int buf) {   // vmcnt-wait + pack + LDS write
        unsigned char* ksb = lds + buf * 8192;
        unsigned char* vsb = lds + 16384 + buf * 8192;
        const int len = seglen(s);
        const int c = tid >> 2, q4 = tid & 3;
        if (c < len) {
            u32x4 lo, hi;
            lo.x = pkt(kreg[0].x,kreg[0].y); lo.y = pkt(kreg[0].z,kreg[0].w);
            lo.z = pkt(kreg[1].x,kreg[1].y); lo.w = pkt(kreg[1].z,kreg[1].w);
            hi.x = pkt(kreg[2].x,kreg[2].y); hi.y = pkt(kreg[2].z,kreg[2].w);
            hi.z = pkt(kreg[3].x,kreg[3].y); hi.w = pkt(kreg[3].z,kreg[3].w);
            const unsigned b  = (unsigned)(c*128 + q4*32);
            const unsigned sw = ((unsigned)(c & 7)) << 4;
            *(u32x4*)(ksb + (b ^ sw))        = lo;
            *(u32x4*)(ksb + ((b ^ sw) ^ 16)) = hi;
        }
        const int c0 = (tid >> 5) * 8, d0 = (tid & 31) * 2;
        if (c0 < len) {
            u32x4 t0, t1;
            t0.x = pkt(vreg[0].x,vreg[1].x); t0.y = pkt(vreg[2].x,vreg[3].x);
            t0.z = pkt(vreg[4].x,vreg[5].x); t0.w = pkt(vreg[6].x,vreg[7].x);
            t1.x = pkt(vreg[0].y,vreg[1].y); t1.y = pkt(vreg[2].y,vreg[3].y);
            t1.z = pkt(vreg[4].y,vreg[5].y); t1.w = pkt(vreg[6].y,vreg[7].y);
            const unsigned b0 = (unsigned)(d0*128 + c0*2)     ^ (((unsigned)(d0 & 7)) << 4);
            const unsigned b1 = (unsigned)((d0+1)*128 + c0*2) ^ (((unsigned)((d0+1) & 7)) << 4);
            *(u32x4*)(vsb + b0) = t0;
            *(u32x4*)(vsb + b1) = t1;
        }
    };

    auto compute = [&](int s, int buf) {
        if (s >= 10 && wv != 0) return;      // special block: only wave 0's rows
        const int nn = (s == 9) ? 3 : ((s == 11) ? 2 : 4);
        const unsigned char* ksb = lds + buf * 8192;
        const unsigned char* vsb = lds + 16384 + buf * 8192;
        unsigned char* ps = lds + 32768 + wv * 2048;

        f32x4 sf[4];
#pragma unroll
        for (int n = 0; n < 4; ++n) sf[n] = (f32x4){0.f,0.f,0.f,0.f};

        __builtin_amdgcn_s_setprio(1);
#pragma unroll
        for (int n = 0; n < 4; ++n) if (n < nn) {
            const int c = lm + 16*n;
#pragma unroll
            for (int kk = 0; kk < 2; ++kk) {
                const unsigned byte = (unsigned)(c*128 + kk*64 + g*16) ^ (((unsigned)(c & 7)) << 4);
                const short8 kf = *(const short8*)(ksb + byte);
                sf[n] = __builtin_amdgcn_mfma_f32_16x16x32_bf16(qa[kk], kf, sf[n], 0, 0, 0);
            }
        }
        __builtin_amdgcn_s_setprio(0);

        if (s >= 8) {
#pragma unroll
            for (int n = 0; n < 4; ++n) if (n < nn) {
                const int p = lm + 16*n;
#pragma unroll
                for (int i = 0; i < 4; ++i)
                    if (!maskOf(s, p, arow[i], A)) sf[n][i] = -1e30f;
            }
        }

        // online softmax with defer-max (THR=8)
        float tmx[4]; bool need = false;
#pragma unroll
        for (int i = 0; i < 4; ++i) {
            float t = sf[0][i];
#pragma unroll
            for (int n = 1; n < 4; ++n) if (n < nn) t = fmaxf(t, sf[n][i]);
            t = fmaxf(t, __shfl_xor(t, 1));
            t = fmaxf(t, __shfl_xor(t, 2));
            t = fmaxf(t, __shfl_xor(t, 4));
            t = fmaxf(t, __shfl_xor(t, 8));
            tmx[i] = t;
            need = need || (t > mrun[i] + 8.f);
        }
        if (__any(need)) {
#pragma unroll
            for (int i = 0; i < 4; ++i) {
                const float nm = fmaxf(mrun[i], tmx[i]);
                const float al = __expf(mrun[i] - nm);
                mrun[i] = nm; lpar[i] *= al;
#pragma unroll
                for (int nv = 0; nv < 4; ++nv) o[nv][i] *= al;
            }
        }
        const int nwr = (nn + 1) & ~1;       // 4,4,2: zero-fill n=3 when nn==3
#pragma unroll
        for (int i = 0; i < 4; ++i) {
            const int row = g*4 + i;
            const unsigned sw = ((unsigned)(row & 7)) << 4;
            float psum = 0.f;
#pragma unroll
            for (int n = 0; n < 4; ++n) if (n < nwr) {
                const float p = (n < nn) ? __expf(sf[n][i] - mrun[i]) : 0.f;
                psum += p;
                const unsigned byte = ((unsigned)(row*128 + (lm + 16*n)*2)) ^ sw;
                *(unsigned short*)(ps + byte) = (unsigned short)(pkt(p, 0.f) & 0xffffu);
            }
            lpar[i] += psum;
        }

        short8 pa[2];
#pragma unroll
        for (int kpv = 0; kpv < 2; ++kpv) if (2*kpv < nn) {
            const unsigned byte = ((unsigned)(lm*128 + kpv*64 + g*16)) ^ (((unsigned)(lm & 7)) << 4);
            pa[kpv] = *(const short8*)(ps + byte);
        }
        __builtin_amdgcn_s_setprio(1);
#pragma unroll
        for (int nv = 0; nv < 4; ++nv)
#pragma unroll
        for (int kpv = 0; kpv < 2; ++kpv) if (2*kpv < nn) {
            const int vd = lm + 16*nv;
            const unsigned byte = ((unsigned)(vd*128 + kpv*64 + g*16)) ^ (((unsigned)(vd & 7)) << 4);
            const short8 vb = *(const short8*)(vsb + byte);
            o[nv] = __builtin_amdgcn_mfma_f32_16x16x32_bf16(pa[kpv], vb, o[nv], 0, 0, 0);
        }
        __builtin_amdgcn_s_setprio(0);
    };

    stage_load(0);
    stage_write(0, 0);
    __syncthreads();
    for (int s = 0; s < nseg; ++s) {
        const bool pre = (s + 1 < nseg);
        if (pre) stage_load(s + 1);          // issue loads EARLY (T14)
        compute(s, s & 1);                   // hides load latency
        if (pre) stage_write(s + 1, (s + 1) & 1);   // pack+write LATE
        __syncthreads();
    }

    // epilogue: reduce row sums across the 16-lane group, normalize, store fp32
#pragma unroll
    for (int i = 0; i < 4; ++i) {
        float v = lpar[i];
        v += __shfl_xor(v, 1);
        v += __shfl_xor(v, 2);
        v += __shfl_xor(v, 4);
        v += __shfl_xor(v, 8);
        const float inv = 1.f / v;
        float* op = Out + ((size_t)bh * kS + rowbase + g*4 + i) * kD + lm;
#pragma unroll
        for (int nv = 0; nv < 4; ++nv)
            op[16*nv] = o[nv][i] * inv;
    }
}

} // namespace

extern "C" void kernel_launch(void* const* d_in, const int* in_sizes, int n_in,
                              void* d_out, int out_size, void* d_ws, size_t ws_size,
                              hipStream_t stream) {
    const float* q = (const float*)d_in[0];
    const float* k = (const float*)d_in[1];
    const float* v = (const float*)d_in[2];
    // d_in[3] (mask) is a pure function of (S,STRIDE,EXPR) reproduced in-kernel.
    float* out = (float*)d_out;
    dim3 grid(1024), block(256);
    hipLaunchKernelGGL(sparse_attn5, grid, block, 0, stream, q, k, v, out);
}

// Round 8
// 69.420 us; speedup vs baseline: 1.4595x; 1.0511x over previous
//
#include <hip/hip_runtime.h>
#include <math.h>

// SparseMultiheadAttention B=2,H=16,S=2048,DH=64, STRIDE=128, EXPR=32, bidirectional.
// Mask factorization (HW-validated rounds 0-2):
//   allowed(i,c) = (c&127)>=96 | ((c&127)==0 && c>0) | ((c>>7)==a(i))
//   a(i) = (i>>7) - ((i&127)==0 && i>0)
// R8: swapped QK^T (S^T = mfma(K,Q)) so each lane owns one q-row (q = lane&15):
//   softmax row-max = in-lane tree + 2 shfls (was 16); mrun/lpar scalars;
//   rescale/normalize redistributed to C-layout rows via 4 __shfl.
// Schedule = R5 (proven 74.8us): stage(s+1) -> compute(s) -> barrier, dbuf LDS.
// T14 reverted: its 32 held VGPRs pushed total regs past the 128/wave occupancy
// cliff (R7: occupancy 38->19%) and netted only ~2%.
// Block = 64 rows (4 waves x 16 rows), grid = 32 bh x 32 row-blocks = 1024.
// 64-col segments, A = row-block's 128-block = R64>>1:
//   s0..7 : summary pairs [256s+96,+128) u [256s+224,+256)       no mask
//   s8    : local [128A, +64)                                     mask a_row==A
//   s9    : local [128A+64,+96) (32) + checkpoints {128k,k=1..15}+pad (16), nn=3
//   s10/11: special block A-1 (R64 even && >0 only); wave 0 computes.
// Coverage verified per-row (col 128A masked in checkpoint tile, unmasked in s8;
// col 128(A-1) masked in checkpoint tile for special row, unmasked in s10).

namespace {

constexpr int kS = 2048, kD = 64;

typedef __attribute__((ext_vector_type(8))) short short8;
typedef __attribute__((ext_vector_type(4))) float f32x4;
typedef __attribute__((ext_vector_type(4))) unsigned int u32x4;
typedef __attribute__((ext_vector_type(2))) unsigned int u32x2;

__device__ __forceinline__ unsigned f2bf(float f) {           // RNE (Q only)
    unsigned u = __builtin_bit_cast(unsigned, f);
    u += 0x7fffu + ((u >> 16) & 1u);
    return u >> 16;
}
__device__ __forceinline__ unsigned pk2(float a, float b) {   // RNE pair
    return f2bf(a) | (f2bf(b) << 16);
}
__device__ __forceinline__ unsigned pkt(float a, float b) {   // truncating pair: 1 v_perm
    return __builtin_amdgcn_perm(__builtin_bit_cast(unsigned, b),
                                 __builtin_bit_cast(unsigned, a), 0x07060302u);
}

__device__ __forceinline__ int seglen(int s) { return s == 9 ? 48 : (s == 11 ? 32 : 64); }

__device__ __forceinline__ int colOf(int s, int p, int A) {
    if (s < 8)  return 256 * s + (p < 32 ? 96 + p : 192 + p);
    if (s == 8) return 128 * A + p;
    if (s == 9) {
        if (p < 32) return 128 * A + 64 + p;
        const int k = p - 31;                 // 1..16
        return k < 16 ? 128 * k : 2047;       // p=47 pad (always masked)
    }
    if (s == 10) return 128 * (A - 1) + p;
    return 128 * (A - 1) + 64 + p;            // s==11
}
__device__ __forceinline__ bool maskOf(int s, int p, int a_row, int A) {
    if (s < 8)  return true;
    if (s == 8) return a_row == A;
    if (s == 9) return p < 32 ? (a_row == A) : (p < 47 && a_row != (p - 31));
    return a_row == A - 1;                    // s==10/11
}

__global__ __launch_bounds__(256) void sparse_attn6(
    const float* __restrict__ Q, const float* __restrict__ K,
    const float* __restrict__ V, float* __restrict__ Out)
{
    // [0,16K):   K dbuf 2 x 8KB  [c(64)][d(64)] bf16, swz byte ^= (c&7)<<4
    // [16K,32K): V^T dbuf 2 x 8KB [d(64)][c(64)] bf16, swz byte ^= (d&7)<<4
    // [32K,40K): ps 4 waves x 2KB [q(16)][c(64)] bf16, swz byte ^= (q&7)<<4
    __shared__ __align__(16) unsigned char lds[40960];

    const int tid = threadIdx.x;
    const int wv = tid >> 6;
    const int l = tid & 63, g = l >> 4, lm = l & 15;
    const int bh = blockIdx.x >> 5, R64 = blockIdx.x & 31;
    const int A = R64 >> 1;
    const int rowbase = R64 * 64 + wv * 16;
    const bool spec = ((R64 & 1) == 0) && (R64 > 0);
    const int nseg = spec ? 12 : 10;

    const float* Qb = Q + (size_t)bh * kS * kD;
    const float* Kb = K + (size_t)bh * kS * kD;
    const float* Vb = V + (size_t)bh * kS * kD;

    // Q fragment (serves as mfma B-operand in swapped QK: col=q=lm, k=d=g*8+j+32kk)
    short8 qa[2];
#pragma unroll
    for (int kk = 0; kk < 2; ++kk) {
        const float* qp = Qb + (size_t)(rowbase + lm) * kD + kk*32 + g*8;
        float4 a = *(const float4*)qp;
        float4 b = *(const float4*)(qp + 4);
        u32x4 t;
        t.x = pk2(a.x*0.125f, a.y*0.125f);
        t.y = pk2(a.z*0.125f, a.w*0.125f);
        t.z = pk2(b.x*0.125f, b.y*0.125f);
        t.w = pk2(b.z*0.125f, b.w*0.125f);
        qa[kk] = __builtin_bit_cast(short8, t);
    }

    // a-value for this lane's q-row (q = rowbase + lm)
    const int qrow = rowbase + lm;
    const int aq = (qrow >> 7) - (((qrow & 127) == 0 && qrow > 0) ? 1 : 0);

    float mrun = -1e30f, lpar = 0.f;   // scalars: softmax state for q = lm
    f32x4 o[4];                         // O[q=g*4+i][d=lm+16nv]
#pragma unroll
    for (int nv = 0; nv < 4; ++nv) o[nv] = (f32x4){0.f,0.f,0.f,0.f};

    auto stage = [&](int s, int buf) {
        unsigned char* ksb = lds + buf * 8192;
        unsigned char* vsb = lds + 16384 + buf * 8192;
        const int len = seglen(s);
        {   // K: thread (c = tid>>2, q4 = tid&3) loads 16 consecutive d-floats
            const int c = tid >> 2, q4 = tid & 3;
            if (c < len) {
                const int col = colOf(s, c, A);
                const float* kp = Kb + (size_t)col * kD + q4*16;
                float4 k0 = *(const float4*)(kp);
                float4 k1 = *(const float4*)(kp + 4);
                float4 k2 = *(const float4*)(kp + 8);
                float4 k3 = *(const float4*)(kp + 12);
                u32x4 lo, hi;
                lo.x = pkt(k0.x,k0.y); lo.y = pkt(k0.z,k0.w);
                lo.z = pkt(k1.x,k1.y); lo.w = pkt(k1.z,k1.w);
                hi.x = pkt(k2.x,k2.y); hi.y = pkt(k2.z,k2.w);
                hi.z = pkt(k3.x,k3.y); hi.w = pkt(k3.z,k3.w);
                const unsigned b  = (unsigned)(c*128 + q4*32);
                const unsigned sw = ((unsigned)(c & 7)) << 4;
                *(u32x4*)(ksb + (b ^ sw))        = lo;
                *(u32x4*)(ksb + ((b ^ sw) ^ 16)) = hi;
            }
        }
        {   // V^T: thread (c0 = (tid>>5)*8, d0 = (tid&31)*2) gathers 8 cols
            const int c0 = (tid >> 5) * 8, d0 = (tid & 31) * 2;
            if (c0 < len) {
                float2 r[8];
#pragma unroll
                for (int j = 0; j < 8; ++j) {
                    const int col = colOf(s, c0 + j, A);
                    r[j] = *(const float2*)(Vb + (size_t)col * kD + d0);
                }
                u32x4 t0, t1;
                t0.x = pkt(r[0].x,r[1].x); t0.y = pkt(r[2].x,r[3].x);
                t0.z = pkt(r[4].x,r[5].x); t0.w = pkt(r[6].x,r[7].x);
                t1.x = pkt(r[0].y,r[1].y); t1.y = pkt(r[2].y,r[3].y);
                t1.z = pkt(r[4].y,r[5].y); t1.w = pkt(r[6].y,r[7].y);
                const unsigned b0 = (unsigned)(d0*128 + c0*2)     ^ (((unsigned)(d0 & 7)) << 4);
                const unsigned b1 = (unsigned)((d0+1)*128 + c0*2) ^ (((unsigned)((d0+1) & 7)) << 4);
                *(u32x4*)(vsb + b0) = t0;
                *(u32x4*)(vsb + b1) = t1;
            }
        }
    };

    auto compute = [&](int s, int buf) {
        if (s >= 10 && wv != 0) return;      // special block: only wave 0's rows
        const int nn = (s == 9) ? 3 : ((s == 11) ? 2 : 4);
        const unsigned char* ksb = lds + buf * 8192;
        const unsigned char* vsb = lds + 16384 + buf * 8192;
        unsigned char* ps = lds + 32768 + wv * 2048;
        const unsigned swz = ((unsigned)(lm & 7)) << 4;

        // S^T tiles: sf[n][i] = S[q=lm][c = 16n + g*4 + i]
        f32x4 sf[4];
#pragma unroll
        for (int n = 0; n < 4; ++n) sf[n] = (f32x4){0.f,0.f,0.f,0.f};

        __builtin_amdgcn_s_setprio(1);
#pragma unroll
        for (int n = 0; n < 4; ++n) if (n < nn) {
            const int c = lm + 16*n;         // K-fragment row (A-operand)
#pragma unroll
            for (int kk = 0; kk < 2; ++kk) {
                const unsigned byte = (unsigned)(c*128 + kk*64 + g*16) ^ (((unsigned)(c & 7)) << 4);
                const short8 kf = *(const short8*)(ksb + byte);
                sf[n] = __builtin_amdgcn_mfma_f32_16x16x32_bf16(kf, qa[kk], sf[n], 0, 0, 0);
            }
        }
        __builtin_amdgcn_s_setprio(0);

        if (s >= 8) {                        // mask: per lane, q-row = lm
#pragma unroll
            for (int n = 0; n < 4; ++n) if (n < nn) {
#pragma unroll
                for (int i = 0; i < 4; ++i) {
                    const int c = 16*n + g*4 + i;
                    if (!maskOf(s, c, aq, A)) sf[n][i] = -1e30f;
                }
            }
        }

        // row max: in-lane tree + 2 cross-g shfls; defer-max (THR=8)
        float t = -1e30f;
#pragma unroll
        for (int n = 0; n < 4; ++n) if (n < nn) {
            t = fmaxf(t, fmaxf(fmaxf(sf[n][0], sf[n][1]), fmaxf(sf[n][2], sf[n][3])));
        }
        t = fmaxf(t, __shfl_xor(t, 16));
        t = fmaxf(t, __shfl_xor(t, 32));
        const bool need = t > mrun + 8.f;
        if (__any(need)) {
            const float nm = fmaxf(mrun, t);
            const float al = __expf(mrun - nm);
            mrun = nm; lpar *= al;
#pragma unroll
            for (int i = 0; i < 4; ++i) {    // redistribute al to C-layout rows
                const float ali = __shfl(al, (g*4 + i) + 16*g);
#pragma unroll
                for (int nv = 0; nv < 4; ++nv) o[nv][i] *= ali;
            }
        }

        // exp + pack + partial row sum (this lane's 16 of 64 columns)
        const int nwr = (nn + 1) & ~1;       // 4,4,2: zero-fill tile 3 when nn==3
        float psum = 0.f;
        unsigned w0[4], w1[4];
#pragma unroll
        for (int n = 0; n < 4; ++n) if (n < nwr) {
            float p0 = 0.f, p1 = 0.f, p2 = 0.f, p3 = 0.f;
            if (n < nn) {
                p0 = __expf(sf[n][0] - mrun);
                p1 = __expf(sf[n][1] - mrun);
                p2 = __expf(sf[n][2] - mrun);
                p3 = __expf(sf[n][3] - mrun);
                psum += (p0 + p1) + (p2 + p3);
            }
            w0[n] = pkt(p0, p1);
            w1[n] = pkt(p2, p3);
        }
        lpar += psum;

        // P -> ps:  row q=lm, c = 16n + g*4 .. +3  (one b64 per tile)
#pragma unroll
        for (int n = 0; n < 4; ++n) if (n < nwr) {
            u32x2 wpair; wpair.x = w0[n]; wpair.y = w1[n];
            *(u32x2*)(ps + ((unsigned)(lm*128 + 32*n + 8*g) ^ swz)) = wpair;
        }

        // PV: A = P rows (row=q=lm, k=c), B = V^T
        short8 pa[2];
#pragma unroll
        for (int kpv = 0; kpv < 2; ++kpv) if (2*kpv < nn) {
            pa[kpv] = *(const short8*)(ps + ((unsigned)(lm*128 + kpv*64 + g*16) ^ swz));
        }
        __builtin_amdgcn_s_setprio(1);
#pragma unroll
        for (int nv = 0; nv < 4; ++nv)
#pragma unroll
        for (int kpv = 0; kpv < 2; ++kpv) if (2*kpv < nn) {
            const int vd = lm + 16*nv;
            const unsigned byte = ((unsigned)(vd*128 + kpv*64 + g*16)) ^ (((unsigned)(vd & 7)) << 4);
            const short8 vb = *(const short8*)(vsb + byte);
            o[nv] = __builtin_amdgcn_mfma_f32_16x16x32_bf16(pa[kpv], vb, o[nv], 0, 0, 0);
        }
        __builtin_amdgcn_s_setprio(0);
    };

    stage(0, 0);
    __syncthreads();
    for (int s = 0; s < nseg; ++s) {
        if (s + 1 < nseg) stage(s + 1, (s + 1) & 1);   // issue-ahead, dbl-buffered
        compute(s, s & 1);
        __syncthreads();
    }

    // epilogue: total row sum for q=lm, redistribute 1/l to C-layout rows, store
    float v = lpar;
    v += __shfl_xor(v, 16);
    v += __shfl_xor(v, 32);
    const float linv = 1.f / v;
#pragma unroll
    for (int i = 0; i < 4; ++i) {
        const float inv = __shfl(linv, (g*4 + i) + 16*g);
        float* op = Out + ((size_t)bh * kS + rowbase + g*4 + i) * kD + lm;
#pragma unroll
        for (int nv = 0; nv < 4; ++nv)
            op[16*nv] = o[nv][i] * inv;
    }
}

} // namespace

extern "C" void kernel_launch(void* const* d_in, const int* in_sizes, int n_in,
                              void* d_out, int out_size, void* d_ws, size_t ws_size,
                              hipStream_t stream) {
    const float* q = (const float*)d_in[0];
    const float* k = (const float*)d_in[1];
    const float* v = (const float*)d_in[2];
    // d_in[3] (mask) is a pure function of (S,STRIDE,EXPR) reproduced in-kernel.
    float* out = (float*)d_out;
    dim3 grid(1024), block(256);
    hipLaunchKernelGGL(sparse_attn6, grid, block, 0, stream, q, k, v, out);
}